// Round 1
// 419.856 us; speedup vs baseline: 1.6165x; 1.6165x over previous
//
#include <hip/hip_runtime.h>

#define BB    32
#define NSEQ  1024
#define CDIM  768
#define NH    12
#define HD    64
#define LKEYS 128
#define NPOOL 128

typedef __bf16 bf16x8 __attribute__((ext_vector_type(8)));
typedef float  f32x4  __attribute__((ext_vector_type(4)));

__device__ __forceinline__ ushort f2bf(float f) {
    union { float f; uint u; } v; v.f = f;
    uint u = v.u;
    uint r = u + 0x7FFFu + ((u >> 16) & 1u);   // RNE
    return (ushort)(r >> 16);
}
__device__ __forceinline__ uint pack2(float x, float y) {
    return (uint)f2bf(x) | ((uint)f2bf(y) << 16);
}

// ---------------------------------------------------------------------------
// 0a) fp32 -> bf16 bulk convert (8 elements / thread)
// ---------------------------------------------------------------------------
__global__ __launch_bounds__(256) void cvt_bf16_kernel(const float* __restrict__ src,
                                                       ushort* __restrict__ dst, int n8)
{
    int idx = blockIdx.x * 256 + threadIdx.x;
    if (idx >= n8) return;
    float4 a = ((const float4*)src)[idx * 2];
    float4 b = ((const float4*)src)[idx * 2 + 1];
    uint4 o;
    o.x = pack2(a.x, a.y); o.y = pack2(a.z, a.w);
    o.z = pack2(b.x, b.y); o.w = pack2(b.z, b.w);
    ((uint4*)dst)[idx] = o;
}

// ---------------------------------------------------------------------------
// 0b) transpose + convert: dst[c*R + r] = bf16(src[r*C + c])
// ---------------------------------------------------------------------------
__global__ __launch_bounds__(256) void transpose_cvt_kernel(const float* __restrict__ src,
                                                            ushort* __restrict__ dst,
                                                            int R, int C)
{
    __shared__ ushort tile[32][33];
    int bc = blockIdx.x * 32, br = blockIdx.y * 32;
    int tx = threadIdx.x & 31, ty = threadIdx.x >> 5;    // 32 x 8
#pragma unroll
    for (int i = 0; i < 32; i += 8)
        tile[ty + i][tx] = f2bf(src[(size_t)(br + ty + i) * C + bc + tx]);
    __syncthreads();
#pragma unroll
    for (int i = 0; i < 32; i += 8)
        dst[(size_t)(bc + ty + i) * R + br + tx] = tile[tx][ty + i];
}

// ---------------------------------------------------------------------------
// 1) pool: xp[b,i,c] = 0.5*(x[b,2i,c]+x[b,2i+1,c]) -> bf16, i < 128
// ---------------------------------------------------------------------------
__global__ __launch_bounds__(256) void pool_kernel(const float* __restrict__ x,
                                                   ushort* __restrict__ xp)
{
    int idx = blockIdx.x * 256 + threadIdx.x;        // over B*128*96
    int c8 = idx % 96;
    int t  = idx / 96;
    int i  = t % NPOOL;
    int b  = t / NPOOL;
    if (b >= BB) return;
    const float4* x4 = (const float4*)x;
    size_t base0 = ((size_t)(b * NSEQ + 2 * i)) * 192 + c8 * 2;
    size_t base1 = base0 + 192;
    float4 a0 = x4[base0], a1 = x4[base0 + 1];
    float4 b0 = x4[base1], b1 = x4[base1 + 1];
    uint4 o;
    o.x = pack2(0.5f * (a0.x + b0.x), 0.5f * (a0.y + b0.y));
    o.y = pack2(0.5f * (a0.z + b0.z), 0.5f * (a0.w + b0.w));
    o.z = pack2(0.5f * (a1.x + b1.x), 0.5f * (a1.y + b1.y));
    o.w = pack2(0.5f * (a1.z + b1.z), 0.5f * (a1.w + b1.w));
    ((uint4*)xp)[idx] = o;
}

// ---------------------------------------------------------------------------
// 2) bf16 MFMA GEMM + bias (m97 structure): C[M,N] = A @ Bt^T + bias
//    OBF16: write bf16 output instead of fp32.
// ---------------------------------------------------------------------------
template <bool OBF16>
__global__ __launch_bounds__(256) void mfma_gemm_kernel(
    const ushort* __restrict__ A, const ushort* __restrict__ Bt,
    const float* __restrict__ bias, void* __restrict__ Cout,
    int M, int N, int K)
{
    __shared__ ushort As[128 * 32];
    __shared__ ushort Bs[128 * 32];

    int tid  = threadIdx.x;
    int wave = tid >> 6, lane = tid & 63;
    int m0 = blockIdx.y * 128, n0 = blockIdx.x * 128;
    int wm = wave >> 1, wn = wave & 1;
    int lm = lane & 15, lh = lane >> 4;

    f32x4 acc[4][4] = {};

    for (int k0 = 0; k0 < K; k0 += 32) {
        __syncthreads();
#pragma unroll
        for (int t = 0; t < 2; t++) {
            int flat = wave * 128 + t * 64 + lane;       // 16B-load index
            int row = flat >> 2, kc = (flat & 3) * 8;
            const ushort* gA = A  + (size_t)(m0 + row) * K + k0 + kc;
            const ushort* gB = Bt + (size_t)(n0 + row) * K + k0 + kc;
            __builtin_amdgcn_global_load_lds(
                (const __attribute__((address_space(1))) void*)gA,
                (__attribute__((address_space(3))) void*)(As + (size_t)(wave * 128 + t * 64) * 8),
                16, 0, 0);
            __builtin_amdgcn_global_load_lds(
                (const __attribute__((address_space(1))) void*)gB,
                (__attribute__((address_space(3))) void*)(Bs + (size_t)(wave * 128 + t * 64) * 8),
                16, 0, 0);
        }
        __syncthreads();

        bf16x8 af[4], bfr[4];
#pragma unroll
        for (int i = 0; i < 4; i++)
            af[i] = *(const bf16x8*)((const void*)&As[(wm * 64 + i * 16 + lm) * 32 + lh * 8]);
#pragma unroll
        for (int j = 0; j < 4; j++)
            bfr[j] = *(const bf16x8*)((const void*)&Bs[(wn * 64 + j * 16 + lm) * 32 + lh * 8]);
#pragma unroll
        for (int i = 0; i < 4; i++)
#pragma unroll
            for (int j = 0; j < 4; j++)
                acc[i][j] = __builtin_amdgcn_mfma_f32_16x16x32_bf16(af[i], bfr[j], acc[i][j], 0, 0, 0);
    }

    int crow = m0 + wm * 64, ccol = n0 + wn * 64;
#pragma unroll
    for (int j = 0; j < 4; j++) {
        int col = ccol + j * 16 + lm;
        float bb = bias[col];
        if constexpr (OBF16) {
            ushort* C = (ushort*)Cout;
#pragma unroll
            for (int i = 0; i < 4; i++)
#pragma unroll
                for (int r = 0; r < 4; r++)
                    C[(size_t)(crow + i * 16 + lh * 4 + r) * N + col] = f2bf(acc[i][j][r] + bb);
        } else {
            float* C = (float*)Cout;
#pragma unroll
            for (int i = 0; i < 4; i++)
#pragma unroll
                for (int r = 0; r < 4; r++)
                    C[(size_t)(crow + i * 16 + lh * 4 + r) * N + col] = acc[i][j][r] + bb;
        }
    }
}

// ---------------------------------------------------------------------------
// 3) compress + bank assembly -> bf16 outputs.
//    k_full : [b,h][128 keys][64 d]   bf16 (row-major keys x d)
//    v_fullT: [b,h][64 d][128 keys]   bf16 (TRANSPOSED, so PV B-frag is a
//             contiguous ds_read_b128 in the MFMA attention kernel)
// ---------------------------------------------------------------------------
__global__ __launch_bounds__(256) void compress_kernel(
    const float* __restrict__ kvp,
    const float* __restrict__ Ek, const float* __restrict__ Ev,
    const float* __restrict__ kbank, const float* __restrict__ vbank,
    ushort* __restrict__ kfull, ushort* __restrict__ vfullT)
{
    __shared__ float Es[128 * 64];
    __shared__ float Sl[128 * 64];

    int tid = threadIdx.x;
    int h = blockIdx.x, b = blockIdx.y, which = blockIdx.z;
    const float* E    = which ? Ev : Ek;
    const float* bank = which ? vbank : kbank;

#pragma unroll
    for (int i = 0; i < 8; i++) {
        int flat = tid + i * 256;
        *(float4*)&Es[flat * 4] = *(const float4*)&E[flat * 4];
    }
    const float* src = kvp + (size_t)b * 128 * 1536 + which * 768 + h * HD;
#pragma unroll
    for (int i = 0; i < 8; i++) {
        int flat = tid + i * 256;
        int s = flat >> 4, d4 = flat & 15;
        *(float4*)&Sl[s * 64 + d4 * 4] = *(const float4*)&src[(size_t)s * 1536 + d4 * 4];
    }

    const float* bankbase = bank + (size_t)b * 64 * CDIM + h * HD;
    ushort* outK = kfull  + (size_t)(b * NH + h) * LKEYS * HD;
    ushort* outV = vfullT + (size_t)(b * NH + h) * HD * LKEYS;

    // bank part: rows/cols 64..127
#pragma unroll
    for (int i = 0; i < 4; i++) {
        int flat = tid + i * 256;            // 0..1023
        int j = flat >> 4, d4 = flat & 15;   // bank row j, d-quad d4
        float4 v = *(const float4*)&bankbase[(size_t)j * CDIM + d4 * 4];
        if (!which) {
            ushort4 o;
            o.x = f2bf(v.x); o.y = f2bf(v.y); o.z = f2bf(v.z); o.w = f2bf(v.w);
            *(ushort4*)&outK[(size_t)(64 + j) * HD + d4 * 4] = o;
        } else {
            outV[(size_t)(d4 * 4 + 0) * LKEYS + 64 + j] = f2bf(v.x);
            outV[(size_t)(d4 * 4 + 1) * LKEYS + 64 + j] = f2bf(v.y);
            outV[(size_t)(d4 * 4 + 2) * LKEYS + 64 + j] = f2bf(v.z);
            outV[(size_t)(d4 * 4 + 3) * LKEYS + 64 + j] = f2bf(v.w);
        }
    }
    __syncthreads();

    int tx = tid & 15, ty = tid >> 4;
    float acc[4][4];
#pragma unroll
    for (int i = 0; i < 4; i++)
#pragma unroll
        for (int j = 0; j < 4; j++) acc[i][j] = 0.f;

#pragma unroll 4
    for (int s = 0; s < 128; s++) {
        float4 av = *(const float4*)&Es[s * 64 + ty * 4];
        float4 bv = *(const float4*)&Sl[s * 64 + tx * 4];
        float a[4] = {av.x, av.y, av.z, av.w};
        float bb[4] = {bv.x, bv.y, bv.z, bv.w};
#pragma unroll
        for (int i = 0; i < 4; i++)
#pragma unroll
            for (int j = 0; j < 4; j++)
                acc[i][j] += a[i] * bb[j];
    }
    // compressed part: key c = ty*4+i (0..63), d = tx*4+j
    if (!which) {
#pragma unroll
        for (int i = 0; i < 4; i++) {
            ushort4 o;
            o.x = f2bf(acc[i][0]); o.y = f2bf(acc[i][1]);
            o.z = f2bf(acc[i][2]); o.w = f2bf(acc[i][3]);
            *(ushort4*)&outK[(size_t)(ty * 4 + i) * HD + tx * 4] = o;
        }
    } else {
#pragma unroll
        for (int i = 0; i < 4; i++)
#pragma unroll
            for (int j = 0; j < 4; j++)
                outV[(size_t)(tx * 4 + j) * LKEYS + ty * 4 + i] = f2bf(acc[i][j]);
    }
}

// ---------------------------------------------------------------------------
// 4) MFMA attention: per block 64 queries x 1 head, 4 waves (16 q-rows each).
//    Q: bf16 [32768][768]; K: bf16 [b,h][128][64]; V^T: bf16 [b,h][64][128].
//    QK^T -> in-register softmax (16-lane shfl groups) -> P bf16 via LDS
//    transpose -> PV. All rows padded +8 bf16 => 2-way banks (free, m136).
// ---------------------------------------------------------------------------
__global__ __launch_bounds__(256) void attn_mfma_kernel(
    const ushort* __restrict__ qb, const ushort* __restrict__ kf,
    const ushort* __restrict__ vt, ushort* __restrict__ ob)
{
    __shared__ __align__(16) ushort lds[64 * 72 + 128 * 72 + 64 * 136]; // 44 KB
    ushort* Qs = lds;                        // [64][72]
    ushort* Ks = lds + 64 * 72;              // [128][72]
    ushort* Vs = lds + 64 * 72 + 128 * 72;   // [64][136]  (V^T: d x key)
    ushort* Ps = lds;                        // [64][136]  (aliases Qs+Ks, 8704 <= 13824)

    int tid  = threadIdx.x;
    int wave = tid >> 6, lane = tid & 63;
    int lm = lane & 15, lh = lane >> 4;
    int qt = blockIdx.x, h = blockIdx.y, b = blockIdx.z;

    const ushort* qbase = qb + ((size_t)(b * NSEQ + qt * 64)) * CDIM + h * HD;
    const ushort* kbase = kf + (size_t)(b * NH + h) * LKEYS * HD;
    const ushort* vbase = vt + (size_t)(b * NH + h) * HD * LKEYS;

    // stage Q: 64 rows x 128 B  (2 x 256 threads x 16 B)
#pragma unroll
    for (int it = 0; it < 2; it++) {
        int flat = tid + it * 256;
        int row = flat >> 3, seg = flat & 7;
        *(uint4*)&Qs[row * 72 + seg * 8] = *(const uint4*)&qbase[(size_t)row * CDIM + seg * 8];
    }
    // stage K: 128 rows x 128 B
#pragma unroll
    for (int it = 0; it < 4; it++) {
        int flat = tid + it * 256;
        int row = flat >> 3, seg = flat & 7;
        *(uint4*)&Ks[row * 72 + seg * 8] = *(const uint4*)&kbase[(size_t)row * HD + seg * 8];
    }
    // stage V^T: 64 rows x 256 B
#pragma unroll
    for (int it = 0; it < 4; it++) {
        int flat = tid + it * 256;
        int row = flat >> 4, seg = flat & 15;
        *(uint4*)&Vs[row * 136 + seg * 8] = *(const uint4*)&vbase[(size_t)row * LKEYS + seg * 8];
    }
    __syncthreads();

    // ---- QK^T: wave owns q-rows [wave*16, wave*16+16); 8 col-tiles x 2 k-steps
    f32x4 sacc[8] = {};
    bf16x8 aq[2];
#pragma unroll
    for (int ks = 0; ks < 2; ks++)
        aq[ks] = *(const bf16x8*)((const void*)&Qs[(wave * 16 + lm) * 72 + ks * 32 + lh * 8]);
#pragma unroll
    for (int j = 0; j < 8; j++)
#pragma unroll
        for (int ks = 0; ks < 2; ks++) {
            bf16x8 bk = *(const bf16x8*)((const void*)&Ks[(j * 16 + lm) * 72 + ks * 32 + lh * 8]);
            sacc[j] = __builtin_amdgcn_mfma_f32_16x16x32_bf16(aq[ks], bk, sacc[j], 0, 0, 0);
        }

    // ---- softmax: sacc[j][r] = S[wave*16 + lh*4 + r][j*16 + lm]
    // row-reduce across the 16 lanes sharing lh (masks < 16 stay in group)
    float rinv[4];
#pragma unroll
    for (int r = 0; r < 4; r++) {
        float m = sacc[0][r];
#pragma unroll
        for (int j = 1; j < 8; j++) m = fmaxf(m, sacc[j][r]);
#pragma unroll
        for (int off = 1; off < 16; off <<= 1) m = fmaxf(m, __shfl_xor(m, off, 64));
        float s = 0.f;
#pragma unroll
        for (int j = 0; j < 8; j++) {
            float e = __expf((sacc[j][r] - m) * 0.125f);
            sacc[j][r] = e;
            s += e;
        }
#pragma unroll
        for (int off = 1; off < 16; off <<= 1) s += __shfl_xor(s, off, 64);
        rinv[r] = 1.f / s;
    }

    __syncthreads();   // all waves done reading Qs/Ks before Ps overwrites them
    // write normalized P (bf16) for the PV A-fragment transpose
#pragma unroll
    for (int j = 0; j < 8; j++)
#pragma unroll
        for (int r = 0; r < 4; r++)
            Ps[(size_t)(wave * 16 + lh * 4 + r) * 136 + j * 16 + lm] = f2bf(sacc[j][r] * rinv[r]);
    __syncthreads();

    // ---- PV: O[64][64] = P[64][128] @ V[128][64];  B-frag from V^T rows
    f32x4 oacc[4] = {};
#pragma unroll
    for (int ks = 0; ks < 4; ks++) {
        bf16x8 ap = *(const bf16x8*)((const void*)&Ps[(wave * 16 + lm) * 136 + ks * 32 + lh * 8]);
#pragma unroll
        for (int j = 0; j < 4; j++) {
            bf16x8 bv = *(const bf16x8*)((const void*)&Vs[(j * 16 + lm) * 136 + ks * 32 + lh * 8]);
            oacc[j] = __builtin_amdgcn_mfma_f32_16x16x32_bf16(ap, bv, oacc[j], 0, 0, 0);
        }
    }

    ushort* obase = ob + ((size_t)(b * NSEQ + qt * 64)) * CDIM + h * HD;
#pragma unroll
    for (int j = 0; j < 4; j++)
#pragma unroll
        for (int r = 0; r < 4; r++)
            obase[(size_t)(wave * 16 + lh * 4 + r) * CDIM + j * 16 + lm] = f2bf(oacc[j][r]);
}

// ---------------------------------------------------------------------------
// launch
// ---------------------------------------------------------------------------
extern "C" void kernel_launch(void* const* d_in, const int* in_sizes, int n_in,
                              void* d_out, int out_size, void* d_ws, size_t ws_size,
                              hipStream_t stream)
{
    const float* x     = (const float*)d_in[0];
    const float* Wqkv  = (const float*)d_in[1];
    const float* bqkv  = (const float*)d_in[2];
    const float* Ek    = (const float*)d_in[3];
    const float* Ev    = (const float*)d_in[4];
    const float* Wproj = (const float*)d_in[5];
    const float* bproj = (const float*)d_in[6];
    const float* kbank = (const float*)d_in[7];
    const float* vbank = (const float*)d_in[8];
    float* out = (float*)d_out;
    float* ws  = (float*)d_ws;

    // workspace layout (float units), 31,064,064 f = 124 MB total.
    // time-disjoint aliases:
    //   kvp (KV gemm -> compress) dies before qb_bf (Q gemm) is written.
    //   x_bf (cvt -> Q gemm) dies before aob (attn out) is written.
    float*  kvp    = ws;                              //  6,291,456 f
    ushort* qb_bf  = (ushort*)ws;                     // 25,165,824 us (alias kvp)
    ushort* x_bf   = (ushort*)(ws + 12582912);        // 25,165,824 us
    ushort* aob    = x_bf;                            // alias (x_bf dead)
    ushort* xp_bf  = (ushort*)(ws + 25165824);        //  3,145,728 us
    ushort* Wq_t   = (ushort*)(ws + 26738688);        //  1,769,472 us (2304 x 768)
    ushort* Wp_t   = (ushort*)(ws + 27623424);        //    589,824 us (768 x 768)
    ushort* k_full = (ushort*)(ws + 27918336);        //  3,145,728 us bf16
    ushort* v_fullT= (ushort*)(ws + 29491200);        //  3,145,728 us bf16 (transposed)

    cvt_bf16_kernel<<<12288, 256, 0, stream>>>(x, x_bf, 3145728);
    transpose_cvt_kernel<<<dim3(72, 24), 256, 0, stream>>>(Wqkv, Wq_t, CDIM, 3 * CDIM);
    transpose_cvt_kernel<<<dim3(24, 24), 256, 0, stream>>>(Wproj, Wp_t, CDIM, CDIM);
    pool_kernel<<<1536, 256, 0, stream>>>(x, xp_bf);

    // KV projection: 4096 x 1536 fp32 out (feeds fp32 compress)
    mfma_gemm_kernel<false><<<dim3(12, 32), 256, 0, stream>>>(
        xp_bf, Wq_t + (size_t)CDIM * CDIM, bqkv + CDIM, kvp, 4096, 2 * CDIM, CDIM);
    compress_kernel<<<dim3(NH, BB, 2), 256, 0, stream>>>(
        kvp, Ek, Ev, kbank, vbank, k_full, v_fullT);

    // Q projection: 32768 x 768, bf16 out (feeds MFMA attention directly)
    mfma_gemm_kernel<true><<<dim3(6, 256), 256, 0, stream>>>(
        x_bf, Wq_t, bqkv, qb_bf, BB * NSEQ, CDIM, CDIM);

    attn_mfma_kernel<<<dim3(16, NH, BB), 256, 0, stream>>>(qb_bf, k_full, v_fullT, aob);

    // output projection (fp32 final out)
    mfma_gemm_kernel<false><<<dim3(6, 256), 256, 0, stream>>>(
        aob, Wp_t, bproj, out, BB * NSEQ, CDIM, CDIM);
}

// Round 2
// 394.174 us; speedup vs baseline: 1.7218x; 1.0652x over previous
//
#include <hip/hip_runtime.h>

#define BB    32
#define NSEQ  1024
#define CDIM  768
#define NH    12
#define HD    64
#define LKEYS 128
#define NPOOL 128

typedef __bf16 bf16x8 __attribute__((ext_vector_type(8)));
typedef float  f32x4  __attribute__((ext_vector_type(4)));

__device__ __forceinline__ ushort f2bf(float f) {
    union { float f; uint u; } v; v.f = f;
    uint u = v.u;
    uint r = u + 0x7FFFu + ((u >> 16) & 1u);   // RNE
    return (ushort)(r >> 16);
}
__device__ __forceinline__ uint pack2(float x, float y) {
    return (uint)f2bf(x) | ((uint)f2bf(y) << 16);
}

// ---------------------------------------------------------------------------
// 0a) fp32 -> bf16 bulk convert (8 elements / thread)
// ---------------------------------------------------------------------------
__global__ __launch_bounds__(256) void cvt_bf16_kernel(const float* __restrict__ src,
                                                       ushort* __restrict__ dst, int n8)
{
    int idx = blockIdx.x * 256 + threadIdx.x;
    if (idx >= n8) return;
    float4 a = ((const float4*)src)[idx * 2];
    float4 b = ((const float4*)src)[idx * 2 + 1];
    uint4 o;
    o.x = pack2(a.x, a.y); o.y = pack2(a.z, a.w);
    o.z = pack2(b.x, b.y); o.w = pack2(b.z, b.w);
    ((uint4*)dst)[idx] = o;
}

// ---------------------------------------------------------------------------
// 0b) transpose + convert: dst[c*R + r] = bf16(src[r*C + c])
// ---------------------------------------------------------------------------
__global__ __launch_bounds__(256) void transpose_cvt_kernel(const float* __restrict__ src,
                                                            ushort* __restrict__ dst,
                                                            int R, int C)
{
    __shared__ ushort tile[32][33];
    int bc = blockIdx.x * 32, br = blockIdx.y * 32;
    int tx = threadIdx.x & 31, ty = threadIdx.x >> 5;    // 32 x 8
#pragma unroll
    for (int i = 0; i < 32; i += 8)
        tile[ty + i][tx] = f2bf(src[(size_t)(br + ty + i) * C + bc + tx]);
    __syncthreads();
#pragma unroll
    for (int i = 0; i < 32; i += 8)
        dst[(size_t)(bc + ty + i) * R + br + tx] = tile[tx][ty + i];
}

// ---------------------------------------------------------------------------
// 1) pool: xp[b,i,c] = 0.5*(x[b,2i,c]+x[b,2i+1,c]) -> bf16, i < 128
// ---------------------------------------------------------------------------
__global__ __launch_bounds__(256) void pool_kernel(const float* __restrict__ x,
                                                   ushort* __restrict__ xp)
{
    int idx = blockIdx.x * 256 + threadIdx.x;        // over B*128*96
    int c8 = idx % 96;
    int t  = idx / 96;
    int i  = t % NPOOL;
    int b  = t / NPOOL;
    if (b >= BB) return;
    const float4* x4 = (const float4*)x;
    size_t base0 = ((size_t)(b * NSEQ + 2 * i)) * 192 + c8 * 2;
    size_t base1 = base0 + 192;
    float4 a0 = x4[base0], a1 = x4[base0 + 1];
    float4 b0 = x4[base1], b1 = x4[base1 + 1];
    uint4 o;
    o.x = pack2(0.5f * (a0.x + b0.x), 0.5f * (a0.y + b0.y));
    o.y = pack2(0.5f * (a0.z + b0.z), 0.5f * (a0.w + b0.w));
    o.z = pack2(0.5f * (a1.x + b1.x), 0.5f * (a1.y + b1.y));
    o.w = pack2(0.5f * (a1.z + b1.z), 0.5f * (a1.w + b1.w));
    ((uint4*)xp)[idx] = o;
}

// ---------------------------------------------------------------------------
// 2) bf16 MFMA GEMM + bias (m97 structure): C[M,N] = A @ Bt^T + bias
//    OBF16: write bf16 output instead of fp32.
//    XCD-aware bijective block swizzle (T1, m204): each XCD consumes a
//    contiguous chunk of flat block ids, x-fastest, so one A row-panel is
//    read entirely within one XCD's L2 (kills the 3x A over-fetch).
// ---------------------------------------------------------------------------
template <bool OBF16>
__global__ __launch_bounds__(256) void mfma_gemm_kernel(
    const ushort* __restrict__ A, const ushort* __restrict__ Bt,
    const float* __restrict__ bias, void* __restrict__ Cout,
    int M, int N, int K)
{
    __shared__ ushort As[128 * 32];
    __shared__ ushort Bs[128 * 32];

    int tid  = threadIdx.x;
    int wave = tid >> 6, lane = tid & 63;

    // ---- XCD swizzle (bijective, m204) ----
    int nwg  = gridDim.x * gridDim.y;
    int bid  = blockIdx.y * gridDim.x + blockIdx.x;
    int q    = nwg >> 3, r = nwg & 7;
    int xcd  = bid & 7, j = bid >> 3;
    int flat = (xcd < r ? xcd * (q + 1) : r * (q + 1) + (xcd - r) * q) + j;
    int n0 = (flat % gridDim.x) * 128;
    int m0 = (flat / gridDim.x) * 128;

    int wm = wave >> 1, wn = wave & 1;
    int lm = lane & 15, lh = lane >> 4;

    f32x4 acc[4][4] = {};

    for (int k0 = 0; k0 < K; k0 += 32) {
        __syncthreads();
#pragma unroll
        for (int t = 0; t < 2; t++) {
            int fl = wave * 128 + t * 64 + lane;         // 16B-load index
            int row = fl >> 2, kc = (fl & 3) * 8;
            const ushort* gA = A  + (size_t)(m0 + row) * K + k0 + kc;
            const ushort* gB = Bt + (size_t)(n0 + row) * K + k0 + kc;
            __builtin_amdgcn_global_load_lds(
                (const __attribute__((address_space(1))) void*)gA,
                (__attribute__((address_space(3))) void*)(As + (size_t)(wave * 128 + t * 64) * 8),
                16, 0, 0);
            __builtin_amdgcn_global_load_lds(
                (const __attribute__((address_space(1))) void*)gB,
                (__attribute__((address_space(3))) void*)(Bs + (size_t)(wave * 128 + t * 64) * 8),
                16, 0, 0);
        }
        __syncthreads();

        bf16x8 af[4], bfr[4];
#pragma unroll
        for (int i = 0; i < 4; i++)
            af[i] = *(const bf16x8*)((const void*)&As[(wm * 64 + i * 16 + lm) * 32 + lh * 8]);
#pragma unroll
        for (int jj = 0; jj < 4; jj++)
            bfr[jj] = *(const bf16x8*)((const void*)&Bs[(wn * 64 + jj * 16 + lm) * 32 + lh * 8]);
#pragma unroll
        for (int i = 0; i < 4; i++)
#pragma unroll
            for (int jj = 0; jj < 4; jj++)
                acc[i][jj] = __builtin_amdgcn_mfma_f32_16x16x32_bf16(af[i], bfr[jj], acc[i][jj], 0, 0, 0);
    }

    int crow = m0 + wm * 64, ccol = n0 + wn * 64;
#pragma unroll
    for (int jj = 0; jj < 4; jj++) {
        int col = ccol + jj * 16 + lm;
        float bb = bias[col];
        if constexpr (OBF16) {
            ushort* C = (ushort*)Cout;
#pragma unroll
            for (int i = 0; i < 4; i++)
#pragma unroll
                for (int rr = 0; rr < 4; rr++)
                    C[(size_t)(crow + i * 16 + lh * 4 + rr) * N + col] = f2bf(acc[i][jj][rr] + bb);
        } else {
            float* C = (float*)Cout;
#pragma unroll
            for (int i = 0; i < 4; i++)
#pragma unroll
                for (int rr = 0; rr < 4; rr++)
                    C[(size_t)(crow + i * 16 + lh * 4 + rr) * N + col] = acc[i][jj][rr] + bb;
        }
    }
}

// ---------------------------------------------------------------------------
// 3) compress + bank assembly -> bf16 outputs.
//    k_full : [b,h][128 keys][64 d]   bf16
//    v_fullT: [b,h][64 d][128 keys]   bf16 (transposed for PV B-frag)
// ---------------------------------------------------------------------------
__global__ __launch_bounds__(256) void compress_kernel(
    const float* __restrict__ kvp,
    const float* __restrict__ Ek, const float* __restrict__ Ev,
    const float* __restrict__ kbank, const float* __restrict__ vbank,
    ushort* __restrict__ kfull, ushort* __restrict__ vfullT)
{
    __shared__ float Es[128 * 64];
    __shared__ float Sl[128 * 64];

    int tid = threadIdx.x;
    int h = blockIdx.x, b = blockIdx.y, which = blockIdx.z;
    const float* E    = which ? Ev : Ek;
    const float* bank = which ? vbank : kbank;

#pragma unroll
    for (int i = 0; i < 8; i++) {
        int flat = tid + i * 256;
        *(float4*)&Es[flat * 4] = *(const float4*)&E[flat * 4];
    }
    const float* src = kvp + (size_t)b * 128 * 1536 + which * 768 + h * HD;
#pragma unroll
    for (int i = 0; i < 8; i++) {
        int flat = tid + i * 256;
        int s = flat >> 4, d4 = flat & 15;
        *(float4*)&Sl[s * 64 + d4 * 4] = *(const float4*)&src[(size_t)s * 1536 + d4 * 4];
    }

    const float* bankbase = bank + (size_t)b * 64 * CDIM + h * HD;
    ushort* outK = kfull  + (size_t)(b * NH + h) * LKEYS * HD;
    ushort* outV = vfullT + (size_t)(b * NH + h) * HD * LKEYS;

    // bank part: rows/cols 64..127
#pragma unroll
    for (int i = 0; i < 4; i++) {
        int flat = tid + i * 256;            // 0..1023
        int j = flat >> 4, d4 = flat & 15;   // bank row j, d-quad d4
        float4 v = *(const float4*)&bankbase[(size_t)j * CDIM + d4 * 4];
        if (!which) {
            ushort4 o;
            o.x = f2bf(v.x); o.y = f2bf(v.y); o.z = f2bf(v.z); o.w = f2bf(v.w);
            *(ushort4*)&outK[(size_t)(64 + j) * HD + d4 * 4] = o;
        } else {
            outV[(size_t)(d4 * 4 + 0) * LKEYS + 64 + j] = f2bf(v.x);
            outV[(size_t)(d4 * 4 + 1) * LKEYS + 64 + j] = f2bf(v.y);
            outV[(size_t)(d4 * 4 + 2) * LKEYS + 64 + j] = f2bf(v.z);
            outV[(size_t)(d4 * 4 + 3) * LKEYS + 64 + j] = f2bf(v.w);
        }
    }
    __syncthreads();

    int tx = tid & 15, ty = tid >> 4;
    float acc[4][4];
#pragma unroll
    for (int i = 0; i < 4; i++)
#pragma unroll
        for (int j = 0; j < 4; j++) acc[i][j] = 0.f;

#pragma unroll 4
    for (int s = 0; s < 128; s++) {
        float4 av = *(const float4*)&Es[s * 64 + ty * 4];
        float4 bv = *(const float4*)&Sl[s * 64 + tx * 4];
        float a[4] = {av.x, av.y, av.z, av.w};
        float bb[4] = {bv.x, bv.y, bv.z, bv.w};
#pragma unroll
        for (int i = 0; i < 4; i++)
#pragma unroll
            for (int j = 0; j < 4; j++)
                acc[i][j] += a[i] * bb[j];
    }
    // compressed part: key c = ty*4+i (0..63), d = tx*4+j
    if (!which) {
#pragma unroll
        for (int i = 0; i < 4; i++) {
            ushort4 o;
            o.x = f2bf(acc[i][0]); o.y = f2bf(acc[i][1]);
            o.z = f2bf(acc[i][2]); o.w = f2bf(acc[i][3]);
            *(ushort4*)&outK[(size_t)(ty * 4 + i) * HD + tx * 4] = o;
        }
    } else {
#pragma unroll
        for (int i = 0; i < 4; i++)
#pragma unroll
            for (int j = 0; j < 4; j++)
                outV[(size_t)(tx * 4 + j) * LKEYS + ty * 4 + i] = f2bf(acc[i][j]);
    }
}

// ---------------------------------------------------------------------------
// 4) MFMA attention: per block 64 queries x 1 head, 4 waves (16 q-rows each).
// ---------------------------------------------------------------------------
__global__ __launch_bounds__(256) void attn_mfma_kernel(
    const ushort* __restrict__ qb, const ushort* __restrict__ kf,
    const ushort* __restrict__ vt, ushort* __restrict__ ob)
{
    __shared__ __align__(16) ushort lds[64 * 72 + 128 * 72 + 64 * 136]; // 44 KB
    ushort* Qs = lds;                        // [64][72]
    ushort* Ks = lds + 64 * 72;              // [128][72]
    ushort* Vs = lds + 64 * 72 + 128 * 72;   // [64][136]  (V^T: d x key)
    ushort* Ps = lds;                        // [64][136]  (aliases Qs+Ks)

    int tid  = threadIdx.x;
    int wave = tid >> 6, lane = tid & 63;
    int lm = lane & 15, lh = lane >> 4;
    int qt = blockIdx.x, h = blockIdx.y, b = blockIdx.z;

    const ushort* qbase = qb + ((size_t)(b * NSEQ + qt * 64)) * CDIM + h * HD;
    const ushort* kbase = kf + (size_t)(b * NH + h) * LKEYS * HD;
    const ushort* vbase = vt + (size_t)(b * NH + h) * HD * LKEYS;

    // stage Q: 64 rows x 128 B
#pragma unroll
    for (int it = 0; it < 2; it++) {
        int flat = tid + it * 256;
        int row = flat >> 3, seg = flat & 7;
        *(uint4*)&Qs[row * 72 + seg * 8] = *(const uint4*)&qbase[(size_t)row * CDIM + seg * 8];
    }
    // stage K: 128 rows x 128 B
#pragma unroll
    for (int it = 0; it < 4; it++) {
        int flat = tid + it * 256;
        int row = flat >> 3, seg = flat & 7;
        *(uint4*)&Ks[row * 72 + seg * 8] = *(const uint4*)&kbase[(size_t)row * HD + seg * 8];
    }
    // stage V^T: 64 rows x 256 B
#pragma unroll
    for (int it = 0; it < 4; it++) {
        int flat = tid + it * 256;
        int row = flat >> 4, seg = flat & 15;
        *(uint4*)&Vs[row * 136 + seg * 8] = *(const uint4*)&vbase[(size_t)row * LKEYS + seg * 8];
    }
    __syncthreads();

    // ---- QK^T
    f32x4 sacc[8] = {};
    bf16x8 aq[2];
#pragma unroll
    for (int ks = 0; ks < 2; ks++)
        aq[ks] = *(const bf16x8*)((const void*)&Qs[(wave * 16 + lm) * 72 + ks * 32 + lh * 8]);
#pragma unroll
    for (int j = 0; j < 8; j++)
#pragma unroll
        for (int ks = 0; ks < 2; ks++) {
            bf16x8 bk = *(const bf16x8*)((const void*)&Ks[(j * 16 + lm) * 72 + ks * 32 + lh * 8]);
            sacc[j] = __builtin_amdgcn_mfma_f32_16x16x32_bf16(aq[ks], bk, sacc[j], 0, 0, 0);
        }

    // ---- softmax (16-lane shfl groups)
    float rinv[4];
#pragma unroll
    for (int r = 0; r < 4; r++) {
        float m = sacc[0][r];
#pragma unroll
        for (int j = 1; j < 8; j++) m = fmaxf(m, sacc[j][r]);
#pragma unroll
        for (int off = 1; off < 16; off <<= 1) m = fmaxf(m, __shfl_xor(m, off, 64));
        float s = 0.f;
#pragma unroll
        for (int j = 0; j < 8; j++) {
            float e = __expf((sacc[j][r] - m) * 0.125f);
            sacc[j][r] = e;
            s += e;
        }
#pragma unroll
        for (int off = 1; off < 16; off <<= 1) s += __shfl_xor(s, off, 64);
        rinv[r] = 1.f / s;
    }

    __syncthreads();
#pragma unroll
    for (int j = 0; j < 8; j++)
#pragma unroll
        for (int r = 0; r < 4; r++)
            Ps[(size_t)(wave * 16 + lh * 4 + r) * 136 + j * 16 + lm] = f2bf(sacc[j][r] * rinv[r]);
    __syncthreads();

    // ---- PV
    f32x4 oacc[4] = {};
#pragma unroll
    for (int ks = 0; ks < 4; ks++) {
        bf16x8 ap = *(const bf16x8*)((const void*)&Ps[(wave * 16 + lm) * 136 + ks * 32 + lh * 8]);
#pragma unroll
        for (int j = 0; j < 4; j++) {
            bf16x8 bv = *(const bf16x8*)((const void*)&Vs[(j * 16 + lm) * 136 + ks * 32 + lh * 8]);
            oacc[j] = __builtin_amdgcn_mfma_f32_16x16x32_bf16(ap, bv, oacc[j], 0, 0, 0);
        }
    }

    ushort* obase = ob + ((size_t)(b * NSEQ + qt * 64)) * CDIM + h * HD;
#pragma unroll
    for (int j = 0; j < 4; j++)
#pragma unroll
        for (int r = 0; r < 4; r++)
            obase[(size_t)(wave * 16 + lh * 4 + r) * CDIM + j * 16 + lm] = f2bf(oacc[j][r]);
}

// ---------------------------------------------------------------------------
// launch
// ---------------------------------------------------------------------------
extern "C" void kernel_launch(void* const* d_in, const int* in_sizes, int n_in,
                              void* d_out, int out_size, void* d_ws, size_t ws_size,
                              hipStream_t stream)
{
    const float* x     = (const float*)d_in[0];
    const float* Wqkv  = (const float*)d_in[1];
    const float* bqkv  = (const float*)d_in[2];
    const float* Ek    = (const float*)d_in[3];
    const float* Ev    = (const float*)d_in[4];
    const float* Wproj = (const float*)d_in[5];
    const float* bproj = (const float*)d_in[6];
    const float* kbank = (const float*)d_in[7];
    const float* vbank = (const float*)d_in[8];
    float* out = (float*)d_out;
    float* ws  = (float*)d_ws;

    // workspace layout (float units), time-disjoint aliases as before
    float*  kvp    = ws;                              //  6,291,456 f
    ushort* qb_bf  = (ushort*)ws;                     // 25,165,824 us (alias kvp)
    ushort* x_bf   = (ushort*)(ws + 12582912);        // 25,165,824 us
    ushort* aob    = x_bf;                            // alias (x_bf dead)
    ushort* xp_bf  = (ushort*)(ws + 25165824);        //  3,145,728 us
    ushort* Wq_t   = (ushort*)(ws + 26738688);        //  1,769,472 us (2304 x 768)
    ushort* Wp_t   = (ushort*)(ws + 27623424);        //    589,824 us (768 x 768)
    ushort* k_full = (ushort*)(ws + 27918336);        //  3,145,728 us bf16
    ushort* v_fullT= (ushort*)(ws + 29491200);        //  3,145,728 us bf16 (transposed)

    cvt_bf16_kernel<<<12288, 256, 0, stream>>>(x, x_bf, 3145728);
    transpose_cvt_kernel<<<dim3(72, 24), 256, 0, stream>>>(Wqkv, Wq_t, CDIM, 3 * CDIM);
    transpose_cvt_kernel<<<dim3(24, 24), 256, 0, stream>>>(Wproj, Wp_t, CDIM, CDIM);
    pool_kernel<<<1536, 256, 0, stream>>>(x, xp_bf);

    // KV projection: 4096 x 1536 fp32 out (feeds fp32 compress)
    mfma_gemm_kernel<false><<<dim3(12, 32), 256, 0, stream>>>(
        xp_bf, Wq_t + (size_t)CDIM * CDIM, bqkv + CDIM, kvp, 4096, 2 * CDIM, CDIM);
    compress_kernel<<<dim3(NH, BB, 2), 256, 0, stream>>>(
        kvp, Ek, Ev, kbank, vbank, k_full, v_fullT);

    // Q projection: 32768 x 768, bf16 out (feeds MFMA attention directly)
    mfma_gemm_kernel<true><<<dim3(6, 256), 256, 0, stream>>>(
        x_bf, Wq_t, bqkv, qb_bf, BB * NSEQ, CDIM, CDIM);

    attn_mfma_kernel<<<dim3(16, NH, BB), 256, 0, stream>>>(qb_bf, k_full, v_fullT, aob);

    // output projection (fp32 final out)
    mfma_gemm_kernel<false><<<dim3(6, 256), 256, 0, stream>>>(
        aob, Wp_t, bproj, out, BB * NSEQ, CDIM, CDIM);
}